// Round 4
// baseline (2370.342 us; speedup 1.0000x reference)
//
#include <hip/hip_runtime.h>
#include <stdint.h>

// Problem constants: B=128, S=256, H=512
#define B_ 128
#define S_ 256
#define H_ 512

typedef __attribute__((ext_vector_type(4))) float f32x4;
typedef __attribute__((ext_vector_type(4))) int i32x4;
typedef __attribute__((ext_vector_type(2))) unsigned int u32x2;
typedef __attribute__((ext_vector_type(8))) __bf16 bf16x8;
typedef unsigned long long u64;

// ---------- workspace layout (bytes) ----------
#define OFF_G      0          // 32768 f32 = 131072 B
#define OFF_RSR    131072     // 512 f32
#define OFF_RSH    133120     // 512 f32
#define OFF_FLG    135168     // 64 flags x 64B stride = 4096 B
#define OFF_EX     139264     // 2 parity x 8 groups x 2048 u64 = 262144 B
#define OFF_CBUF   401408     // 128 x 512 f32 = 262144 B
#define OFF_LOGITS 401408     // alias: logits dead before Cb written
#define OFF_BP     663552     // z1_w packed bf16 = 2097152 B
#define OFF_PB     2760704    // scan weights packed bf16 = 1048576 B
// total ~3.81 MB

__device__ __forceinline__ unsigned short f2bf(float f) {
  unsigned u = __builtin_bit_cast(unsigned, f);
  u += 0x7FFFu + ((u >> 16) & 1u);
  return (unsigned short)(u >> 16);
}
__device__ __forceinline__ float fast_sigmoid(float x) {
  return 1.0f / (1.0f + __expf(-x));
}
__device__ __forceinline__ float fast_tanh(float x) {
  return 1.0f - 2.0f / (__expf(2.0f * x) + 1.0f);
}

// Raw barrier with LDS-only drain: does NOT drain vmcnt, so global loads
// issued before it keep flying across (validated by v4's passing run).
__device__ __forceinline__ void bar_lgkm() {
  asm volatile("s_waitcnt lgkmcnt(0)" ::: "memory");
  __builtin_amdgcn_s_barrier();
  __builtin_amdgcn_sched_barrier(0);
}

// ---------------------------------------------------------------------------
// Prep 1: pack z1_w (2048x512 f32) -> bf16, layout Bp[(k>>3)*512+n][k&7]
// ---------------------------------------------------------------------------
__global__ void k_prep_bp(const float* __restrict__ z1w,
                          unsigned short* __restrict__ Bp) {
  int t = blockIdx.x * blockDim.x + threadIdx.x;  // < 2048*512
  int k = t >> 9, n = t & 511;
  Bp[((k >> 3) * 512 + n) * 8 + (k & 7)] = f2bf(z1w[t]);
}

// ---------------------------------------------------------------------------
// Prep 2: pack Ur,U into per-(mem 0..7, wave 0..7, ktile 0..15, lane) MFMA
// B-fragments. mat = w>>2 (0=Ur,1=U), nt = w&3; n = mem*64 + nt*16 + (l&15).
// ---------------------------------------------------------------------------
__global__ void k_prep_pb(const float* __restrict__ Ur,
                          const float* __restrict__ U,
                          unsigned short* __restrict__ PB) {
  int t = blockIdx.x * blockDim.x + threadIdx.x;  // < 524288
  int j = t & 7;
  int l = (t >> 3) & 63;
  int kt = (t >> 9) & 15;
  int w = (t >> 13) & 7;
  int mem = t >> 16;  // 0..7
  int k = kt * 32 + ((l >> 4) & 3) * 8 + j;
  int n = mem * 64 + (w & 3) * 16 + (l & 15);
  const float* src = (w >> 2) ? U : Ur;
  PB[t] = f2bf(src[k * 512 + n]);
}

// ---------------------------------------------------------------------------
// Prep 3: row sums of Wr and W ('bsh,hk->bsh' collapses to these)
// ---------------------------------------------------------------------------
__global__ void k_prep_rs(const float* __restrict__ Wr,
                          const float* __restrict__ W,
                          float* __restrict__ rsr, float* __restrict__ rsh) {
  __shared__ float red[4];
  int h2 = blockIdx.x;
  int t = threadIdx.x;
  const float* M = (h2 >= 512) ? W : Wr;
  int h = h2 & 511;
  float sv = M[h * 512 + t] + M[h * 512 + 256 + t];
#pragma unroll
  for (int mask = 1; mask < 64; mask <<= 1) sv += __shfl_xor(sv, mask, 64);
  if ((t & 63) == 0) red[t >> 6] = sv;
  __syncthreads();
  if (t == 0) {
    float tot = red[0] + red[1] + red[2] + red[3];
    ((h2 >= 512) ? rsh : rsr)[h] = tot;
  }
}

// ---------------------------------------------------------------------------
// Gate GEMM + fused tanh/dot epilogue (unchanged — not the bottleneck yet)
// ---------------------------------------------------------------------------
__global__ __launch_bounds__(512, 4) void k_gate(
    const float* __restrict__ facts, const float* __restrict__ questions,
    const float* __restrict__ prevM, const float* __restrict__ z1b,
    const float* __restrict__ z2w, const unsigned short* __restrict__ Bp,
    float* __restrict__ logits) {
  __shared__ float qS[512], mS[512], z1bS[512], z2wS[512];
  __shared__ unsigned short At[64 * 40];
  __shared__ unsigned short Bt[16384];
  __shared__ float lp[64 * 4];
  const int tid = threadIdx.x;
  const int row0 = blockIdx.x * 64;
  const int b = row0 >> 8;
  const int s0 = row0 & 255;
  qS[tid] = questions[b * 512 + tid];
  mS[tid] = prevM[b * 512 + tid];
  z1bS[tid] = z1b[tid];
  z2wS[tid] = z2w[tid];
  const int w = tid >> 6, l = tid & 63;
  const int mgrp = w & 1, ngrp = w >> 1;
  const int lm = l & 15, lk = l >> 4;
  f32x4 acc[2][8];
#pragma unroll
  for (int a = 0; a < 2; ++a)
#pragma unroll
    for (int i = 0; i < 8; ++i) acc[a][i] = (f32x4){0.f, 0.f, 0.f, 0.f};
  const int arow = tid >> 3, ac = tid & 7;
  const float* fbase = facts + ((size_t)(b * 256 + s0 + arow)) * 512 + ac * 4;

  for (int kb = 0; kb < 64; ++kb) {
    __syncthreads();
    const int part = kb >> 4;          // 0: f*q, 1: f*m, 2: |f-q|, 3: |f-m|
    const int h0 = (kb & 15) * 32;
    f32x4 fv = *(const f32x4*)(fbase + h0);
    f32x4 ov = (part & 1) ? *(const f32x4*)&mS[h0 + ac * 4]
                          : *(const f32x4*)&qS[h0 + ac * 4];
    float z0, z1, z2, z3;
    if (part < 2) {
      z0 = fv[0] * ov[0]; z1 = fv[1] * ov[1];
      z2 = fv[2] * ov[2]; z3 = fv[3] * ov[3];
    } else {
      z0 = fabsf(fv[0] - ov[0]); z1 = fabsf(fv[1] - ov[1]);
      z2 = fabsf(fv[2] - ov[2]); z3 = fabsf(fv[3] - ov[3]);
    }
    unsigned p0 = (unsigned)f2bf(z0) | ((unsigned)f2bf(z1) << 16);
    unsigned p1 = (unsigned)f2bf(z2) | ((unsigned)f2bf(z3) << 16);
    u32x2 pk = {p0, p1};
    *(u32x2*)&At[arow * 40 + ac * 4] = pk;
    const char* bsrc = (const char*)Bp + (size_t)kb * 32768;
#pragma unroll
    for (int i = 0; i < 4; ++i)
      *(i32x4*)((char*)Bt + i * 8192 + tid * 16) =
          *(const i32x4*)(bsrc + i * 8192 + tid * 16);
    __syncthreads();
    bf16x8 af[2];
#pragma unroll
    for (int mi = 0; mi < 2; ++mi) {
      i32x4 av = *(const i32x4*)&At[((mgrp * 2 + mi) * 16 + lm) * 40 + lk * 8];
      af[mi] = __builtin_bit_cast(bf16x8, av);
    }
#pragma unroll
    for (int i = 0; i < 8; ++i) {
      const int nt = ngrp * 8 + i;
      i32x4 bv = *(const i32x4*)&Bt[lk * 4096 + (nt * 16 + lm) * 8];
      bf16x8 bf = __builtin_bit_cast(bf16x8, bv);
      acc[0][i] = __builtin_amdgcn_mfma_f32_16x16x32_bf16(af[0], bf, acc[0][i], 0, 0, 0);
      acc[1][i] = __builtin_amdgcn_mfma_f32_16x16x32_bf16(af[1], bf, acc[1][i], 0, 0, 0);
    }
  }
  float pr_[2][4];
#pragma unroll
  for (int mi = 0; mi < 2; ++mi)
#pragma unroll
    for (int r = 0; r < 4; ++r) pr_[mi][r] = 0.f;
#pragma unroll
  for (int i = 0; i < 8; ++i) {
    const int n_i = (ngrp * 8 + i) * 16 + lm;
    const float zb = z1bS[n_i], zw = z2wS[n_i];
#pragma unroll
    for (int mi = 0; mi < 2; ++mi)
#pragma unroll
      for (int r = 0; r < 4; ++r)
        pr_[mi][r] += fast_tanh(acc[mi][i][r] + zb) * zw;
  }
#pragma unroll
  for (int mask = 1; mask < 16; mask <<= 1)
#pragma unroll
    for (int mi = 0; mi < 2; ++mi)
#pragma unroll
      for (int r = 0; r < 4; ++r)
        pr_[mi][r] += __shfl_xor(pr_[mi][r], mask, 64);
  if (lm == 0) {
#pragma unroll
    for (int mi = 0; mi < 2; ++mi)
#pragma unroll
      for (int r = 0; r < 4; ++r)
        lp[((mgrp * 2 + mi) * 16 + lk * 4 + r) * 4 + ngrp] = pr_[mi][r];
  }
  __syncthreads();
  if (tid < 64)
    logits[row0 + tid] =
        lp[tid * 4] + lp[tid * 4 + 1] + lp[tid * 4 + 2] + lp[tid * 4 + 3];
}

// ---------------------------------------------------------------------------
// Softmax over S per batch (z2_b dropped: shift-invariant, exact)
// ---------------------------------------------------------------------------
__global__ void k_softmax(const float* __restrict__ logits,
                          float* __restrict__ G) {
  __shared__ float red[4], red2[4];
  int b = blockIdx.x, t = threadIdx.x;
  float v = logits[b * 256 + t];
  float mx = v;
#pragma unroll
  for (int mask = 1; mask < 64; mask <<= 1)
    mx = fmaxf(mx, __shfl_xor(mx, mask, 64));
  if ((t & 63) == 0) red[t >> 6] = mx;
  __syncthreads();
  mx = fmaxf(fmaxf(red[0], red[1]), fmaxf(red[2], red[3]));
  float e = __expf(v - mx);
  float sm = e;
#pragma unroll
  for (int mask = 1; mask < 64; mask <<= 1) sm += __shfl_xor(sm, mask, 64);
  if ((t & 63) == 0) red2[t >> 6] = sm;
  __syncthreads();
  sm = red2[0] + red2[1] + red2[2] + red2[3];
  G[b * 256 + t] = e / sm;
}

// ---------------------------------------------------------------------------
// Scan v7: v3 grouping + v4's HW-validated lean protocol, single cohort.
//
// 64 blocks = 8 groups x 8 members; g = blockIdx.x & 7 so under round-robin
// dispatch all 8 members of a group share one XCD (locality HEURISTIC only;
// correctness is agent-scope and placement-independent). Member owns a
// 64-wide n-slice; weights VGPR-resident.
//
// Per step:
//  [A] place last step's gathered C units (loop-carried VGPRs; compiler
//      inserts the counted vmcnt wait exactly before these LDS stores)
//  BAR1 (lgkm-only) -> [B] MFMA matvec -> outb -> BAR2 (lgkm-only)
//  [C] ew update (tid<256): own slice straight into A-LDS + one 8B
//      agent-relaxed publish store per thread
//  [D] per-thread vmcnt(0) (publish drain; nothing else outstanding) +
//      raw s_barrier
//  [E] tid0 raises flag (relaxed agent, monotone tag)
//  [F] per-thread fused poll+gather: each thread acquire-polls EXACTLY the
//      one member it gathers from, then issues 4 relaxed 8B loads that fly
//      across the step boundary into [A] of s+1
//  [G] facts/G prefetch (issued after the drain -> never force-drained)
// ---------------------------------------------------------------------------
__global__ __launch_bounds__(512, 1) void k_scan(
    const float* __restrict__ facts, const float* __restrict__ Gm,
    const unsigned short* __restrict__ PB, const float* __restrict__ rsr,
    const float* __restrict__ rsh, const float* __restrict__ br,
    const float* __restrict__ bur, const float* __restrict__ bw,
    const float* __restrict__ bu, u64* __restrict__ EXq,
    unsigned int* __restrict__ FLG, float* __restrict__ Cb) {
  __shared__ __align__(16) unsigned short A[16 * 520];  // 16 x 512 bf16, 1040B pitch
  __shared__ float outb[8 * 272];                       // [w][row16 pitch17]
  const int tid = threadIdx.x;
  const int g = blockIdx.x & 7;    // group (same XCD under %8 round-robin)
  const int mem = blockIdx.x >> 3; // member / n-slice owner
  const int w = tid >> 6, l = tid & 63;
  const int lm = l & 15, lk = (l >> 4) & 3;
  // zero A
  for (int i = tid; i < 2080; i += 512) ((u64*)A)[i] = 0ull;
  // weight fragments resident in VGPRs: this wave = (mat = w>>2, nt = w&3)
  i32x4 bfr[16];
  const char* pb = (const char*)PB + (size_t)(mem * 8 + w) * 16384;
#pragma unroll
  for (int kt = 0; kt < 16; ++kt)
    bfr[kt] = *(const i32x4*)(pb + kt * 1024 + l * 16);
  // elementwise lane (tid<256): thread owns (bb, 4 consecutive n)
  const int bb = tid >> 4;           // 0..15
  const int nq = tid & 15;
  const int n0 = mem * 64 + nq * 4;  // global n base
  f32x4 c_rsr, c_br, c_rsh, c_bw, c_bur, c_bu;
  const float* fptr = nullptr;
  const float* gptr = nullptr;
  f32x4 Cv = (f32x4){0.f, 0.f, 0.f, 0.f};
  f32x4 fct;
  float gval = 0.f;
  if (tid < 256) {
    c_rsr = *(const f32x4*)(rsr + n0);
    c_br  = *(const f32x4*)(br + n0);
    c_rsh = *(const f32x4*)(rsh + n0);
    c_bw  = *(const f32x4*)(bw + n0);
    c_bur = *(const f32x4*)(bur + n0);
    c_bu  = *(const f32x4*)(bu + n0);
    const int batch = g * 16 + bb;
    fptr = facts + (size_t)batch * 131072 + n0;
    gptr = Gm + batch * 256;
    fct = *(const f32x4*)(fptr);   // step-0 prefetch
    gval = gptr[0];
  }
  // gather mapping: thread owns 32B = 4 u64 units (row grow, units gnu0..+3),
  // all sourced from member gsrc. 512 threads x 32B = 16KB = full C tile.
  const int grow = tid >> 5;          // 0..15
  const int gnu0 = (tid & 31) * 4;    // first 8B-unit within row
  const int gsrc = (tid >> 2) & 7;    // the single source member
  u64 gq0 = 0, gq1 = 0, gq2 = 0, gq3 = 0;
  __syncthreads();  // prologue drain (A zeroed, weights loaded)

#pragma unroll 1
  for (int s = 0; s < 256; ++s) {
    // ---- [A] place gathered remote C units (loads issued last step) ----
    if (s > 0 && gsrc != mem) {
      char* dA = (char*)A + grow * 1040 + gnu0 * 8;
      *(u64*)(dA)      = gq0;
      *(u64*)(dA + 8)  = gq1;
      *(u64*)(dA + 16) = gq2;
      *(u64*)(dA + 24) = gq3;
    }
    bar_lgkm();  // BAR1: A fully assembled
    // ---- [B] matvec: (C @ Ur | C @ U) slice via MFMA, two ILP chains ----
    f32x4 acc0 = (f32x4){0.f, 0.f, 0.f, 0.f};
    f32x4 acc1 = (f32x4){0.f, 0.f, 0.f, 0.f};
#pragma unroll
    for (int kt = 0; kt < 16; ++kt) {
      i32x4 av = *(const i32x4*)&A[lm * 520 + kt * 32 + lk * 8];
      bf16x8 afv = __builtin_bit_cast(bf16x8, av);
      bf16x8 bfv = __builtin_bit_cast(bf16x8, bfr[kt]);
      if (kt & 1)
        acc1 = __builtin_amdgcn_mfma_f32_16x16x32_bf16(afv, bfv, acc1, 0, 0, 0);
      else
        acc0 = __builtin_amdgcn_mfma_f32_16x16x32_bf16(afv, bfv, acc0, 0, 0, 0);
    }
    f32x4 accs = acc0 + acc1;
#pragma unroll
    for (int r = 0; r < 4; ++r)
      outb[w * 272 + (lk * 4 + r) * 17 + lm] = accs[r];
    bar_lgkm();  // BAR2: outb ready; all A reads done
    // ---- [C] elementwise update + publish ----
    if (tid < 256) {
      unsigned short pk[4];
#pragma unroll
      for (int r = 0; r < 4; ++r) {
        const int n_loc = nq * 4 + r;
        const float uro = outb[(n_loc >> 4) * 272 + bb * 17 + (n_loc & 15)];
        const float uuo = outb[(4 + (n_loc >> 4)) * 272 + bb * 17 + (n_loc & 15)];
        const float pr = fct[r] * c_rsr[r] + c_br[r];
        const float ph = fct[r] * c_rsh[r] + c_bw[r];
        const float r_ = fast_sigmoid(pr + uro + c_bur[r]);
        const float ht = fast_tanh(ph + r_ * (uuo + c_bu[r]));
        Cv[r] = gval * ht + (1.0f - gval) * Cv[r];
        pk[r] = f2bf(Cv[r]);
      }
      const u64 word = (u64)pk[0] | ((u64)pk[1] << 16) | ((u64)pk[2] << 32) |
                       ((u64)pk[3] << 48);
      // own slice straight into A-LDS (A reads done at BAR2)
      *(u64*)((char*)A + bb * 1040 + n0 * 2) = word;
      // publish payload for the other 7 members
      __hip_atomic_store(
          EXq + (((unsigned)(s & 1) * 8u + (unsigned)g) * 2048u) +
              (unsigned)(bb * 128 + (n0 >> 2)),
          word, __ATOMIC_RELAXED, __HIP_MEMORY_SCOPE_AGENT);
    }
    // ---- [D] drain publish stores (only thing outstanding), rendezvous ----
    asm volatile("s_waitcnt vmcnt(0)" ::: "memory");
    __builtin_amdgcn_s_barrier();
    __builtin_amdgcn_sched_barrier(0);
    // ---- [E] raise our flag ----
    if (tid == 0)
      __hip_atomic_store(FLG + ((unsigned)(g * 8 + mem) << 4),
                         (unsigned)(s + 1), __ATOMIC_RELAXED,
                         __HIP_MEMORY_SCOPE_AGENT);
    __builtin_amdgcn_sched_barrier(0);
    // ---- [F] per-thread fused poll + gather (loads fly across boundary) ----
    if (s < 255) {
      if (gsrc != mem) {
        const unsigned tag = (unsigned)(s + 1);
        const unsigned* fp = FLG + ((unsigned)(g * 8 + gsrc) << 4);
        int guard = 0;
        while (__hip_atomic_load(fp, __ATOMIC_ACQUIRE,
                                 __HIP_MEMORY_SCOPE_AGENT) < tag) {
          __builtin_amdgcn_s_sleep(1);
          if (++guard > (1 << 22)) break;  // hang-safety bailout
        }
        const u64* src = EXq +
            (((unsigned)(s & 1) * 8u + (unsigned)g) * 2048u) +
            (unsigned)(grow * 128 + gnu0);
        gq0 = __hip_atomic_load(src + 0, __ATOMIC_RELAXED,
                                __HIP_MEMORY_SCOPE_AGENT);
        gq1 = __hip_atomic_load(src + 1, __ATOMIC_RELAXED,
                                __HIP_MEMORY_SCOPE_AGENT);
        gq2 = __hip_atomic_load(src + 2, __ATOMIC_RELAXED,
                                __HIP_MEMORY_SCOPE_AGENT);
        gq3 = __hip_atomic_load(src + 3, __ATOMIC_RELAXED,
                                __HIP_MEMORY_SCOPE_AGENT);
      }
      // ---- [G] prefetch next-step inputs (never force-drained) ----
      if (tid < 256) {
        fct = *(const f32x4*)(fptr + (size_t)(s + 1) * 512);
        gval = gptr[s + 1];
      }
    }
  }
  if (tid < 256) *(f32x4*)(Cb + (size_t)(g * 16 + bb) * 512 + n0) = Cv;
}

// ---------------------------------------------------------------------------
// Final: out[b] = relu([prevM | C | questions] @ nm_w + nm_b). 2 batches/WG.
// ---------------------------------------------------------------------------
__global__ __launch_bounds__(512) void k_final(
    const float* __restrict__ prevM, const float* __restrict__ questions,
    const float* __restrict__ Cb, const float* __restrict__ nmw,
    const float* __restrict__ nmb, float* __restrict__ out) {
  __shared__ float cc[2][1536];
  const int t = threadIdx.x;
  const int b0 = blockIdx.x * 2;
  for (int i = t; i < 1536; i += 512) {
#pragma unroll
    for (int bi = 0; bi < 2; ++bi) {
      int bbx = b0 + bi;
      float v;
      if (i < 512) v = prevM[bbx * 512 + i];
      else if (i < 1024) v = Cb[bbx * 512 + i - 512];
      else v = questions[bbx * 512 + i - 1024];
      cc[bi][i] = v;
    }
  }
  __syncthreads();
  const int h = t;
  float a0 = nmb[h], a1 = nmb[h];
#pragma unroll 4
  for (int f = 0; f < 1536; ++f) {
    float wv = nmw[f * 512 + h];
    a0 = fmaf(cc[0][f], wv, a0);
    a1 = fmaf(cc[1][f], wv, a1);
  }
  out[(size_t)b0 * 512 + h] = fmaxf(a0, 0.f);
  out[(size_t)(b0 + 1) * 512 + h] = fmaxf(a1, 0.f);
}

// ---------------------------------------------------------------------------
extern "C" void kernel_launch(void* const* d_in, const int* in_sizes, int n_in,
                              void* d_out, int out_size, void* d_ws,
                              size_t ws_size, hipStream_t stream) {
  const float* facts     = (const float*)d_in[0];
  const float* questions = (const float*)d_in[1];
  const float* prevM     = (const float*)d_in[2];
  const float* z1w       = (const float*)d_in[3];
  const float* z1b       = (const float*)d_in[4];
  const float* z2w       = (const float*)d_in[5];
  // d_in[6] = z2_b: softmax shift-invariant, unused (exact)
  const float* Wr        = (const float*)d_in[7];
  const float* br        = (const float*)d_in[8];
  const float* Ur        = (const float*)d_in[9];
  const float* bur       = (const float*)d_in[10];
  const float* W         = (const float*)d_in[11];
  const float* bw        = (const float*)d_in[12];
  const float* U         = (const float*)d_in[13];
  const float* bu        = (const float*)d_in[14];
  const float* nmw       = (const float*)d_in[15];
  const float* nmb       = (const float*)d_in[16];

  char* ws = (char*)d_ws;
  float* G             = (float*)(ws + OFF_G);
  float* rsr           = (float*)(ws + OFF_RSR);
  float* rsh           = (float*)(ws + OFF_RSH);
  unsigned* FLG        = (unsigned*)(ws + OFF_FLG);
  u64* EXq             = (u64*)(ws + OFF_EX);
  float* Cb            = (float*)(ws + OFF_CBUF);
  float* logits        = (float*)(ws + OFF_LOGITS);
  unsigned short* Bp   = (unsigned short*)(ws + OFF_BP);
  unsigned short* PB   = (unsigned short*)(ws + OFF_PB);

  hipMemsetAsync(FLG, 0, 4096, stream);
  k_prep_bp<<<2048, 512, 0, stream>>>(z1w, Bp);
  k_prep_pb<<<1024, 512, 0, stream>>>(Ur, U, PB);
  k_prep_rs<<<1024, 256, 0, stream>>>(Wr, W, rsr, rsh);
  k_gate<<<512, 512, 0, stream>>>(facts, questions, prevM, z1b, z2w, Bp, logits);
  k_softmax<<<128, 256, 0, stream>>>(logits, G);
  k_scan<<<64, 512, 0, stream>>>(facts, G, PB, rsr, rsh, br, bur, bw, bu, EXq,
                                 FLG, Cb);
  k_final<<<64, 512, 0, stream>>>(prevM, questions, Cb, nmw, nmb, (float*)d_out);
}

// Round 5
// 1340.768 us; speedup vs baseline: 1.7679x; 1.7679x over previous
//
#include <hip/hip_runtime.h>
#include <stdint.h>

// Problem constants: B=128, S=256, H=512
#define B_ 128
#define S_ 256
#define H_ 512

typedef __attribute__((ext_vector_type(4))) float f32x4;
typedef __attribute__((ext_vector_type(4))) int i32x4;
typedef __attribute__((ext_vector_type(2))) unsigned int u32x2;
typedef __attribute__((ext_vector_type(8))) __bf16 bf16x8;
typedef unsigned long long u64;

// ---------- workspace layout (bytes) ----------
#define OFF_G      0          // 32768 f32 = 131072 B
#define OFF_RSR    131072     // 512 f32
#define OFF_RSH    133120     // 512 f32
#define OFF_CBUF   401408     // 128 x 512 f32 = 262144 B
#define OFF_LOGITS 401408     // alias: logits dead before Cb written
#define OFF_BP     663552     // z1_w packed bf16 = 2097152 B
#define OFF_EX     663552     // alias: EX (2 parity x 8 grp x 16 b x 512 n f32
                              // = 524288 B) lives in Bp region, DEAD after
                              // k_gate; poisoned 0xFF stream-ordered pre-scan
#define OFF_PB     2760704    // scan weights packed bf16 = 1048576 B
// total ~3.81 MB (unchanged)

__device__ __forceinline__ unsigned short f2bf(float f) {
  unsigned u = __builtin_bit_cast(unsigned, f);
  u += 0x7FFFu + ((u >> 16) & 1u);
  return (unsigned short)(u >> 16);
}
__device__ __forceinline__ float fast_sigmoid(float x) {
  return 1.0f / (1.0f + __expf(-x));
}
__device__ __forceinline__ float fast_tanh(float x) {
  return 1.0f - 2.0f / (__expf(2.0f * x) + 1.0f);
}

// Raw barrier with LDS-only drain: does NOT drain vmcnt, so global loads
// issued before it keep flying across (validated: v4/v7 passing runs).
__device__ __forceinline__ void bar_lgkm() {
  asm volatile("s_waitcnt lgkmcnt(0)" ::: "memory");
  __builtin_amdgcn_s_barrier();
  __builtin_amdgcn_sched_barrier(0);
}

// ---------------------------------------------------------------------------
// Prep 1: pack z1_w (2048x512 f32) -> bf16, layout Bp[(k>>3)*512+n][k&7]
// ---------------------------------------------------------------------------
__global__ void k_prep_bp(const float* __restrict__ z1w,
                          unsigned short* __restrict__ Bp) {
  int t = blockIdx.x * blockDim.x + threadIdx.x;  // < 2048*512
  int k = t >> 9, n = t & 511;
  Bp[((k >> 3) * 512 + n) * 8 + (k & 7)] = f2bf(z1w[t]);
}

// ---------------------------------------------------------------------------
// Prep 2: pack Ur,U into per-(mem 0..7, wave 0..7, ktile 0..15, lane) MFMA
// B-fragments. mat = w>>2 (0=Ur,1=U), nt = w&3; n = mem*64 + nt*16 + (l&15).
// ---------------------------------------------------------------------------
__global__ void k_prep_pb(const float* __restrict__ Ur,
                          const float* __restrict__ U,
                          unsigned short* __restrict__ PB) {
  int t = blockIdx.x * blockDim.x + threadIdx.x;  // < 524288
  int j = t & 7;
  int l = (t >> 3) & 63;
  int kt = (t >> 9) & 15;
  int w = (t >> 13) & 7;
  int mem = t >> 16;  // 0..7
  int k = kt * 32 + ((l >> 4) & 3) * 8 + j;
  int n = mem * 64 + (w & 3) * 16 + (l & 15);
  const float* src = (w >> 2) ? U : Ur;
  PB[t] = f2bf(src[k * 512 + n]);
}

// ---------------------------------------------------------------------------
// Prep 3: row sums of Wr and W ('bsh,hk->bsh' collapses to these)
// ---------------------------------------------------------------------------
__global__ void k_prep_rs(const float* __restrict__ Wr,
                          const float* __restrict__ W,
                          float* __restrict__ rsr, float* __restrict__ rsh) {
  __shared__ float red[4];
  int h2 = blockIdx.x;
  int t = threadIdx.x;
  const float* M = (h2 >= 512) ? W : Wr;
  int h = h2 & 511;
  float sv = M[h * 512 + t] + M[h * 512 + 256 + t];
#pragma unroll
  for (int mask = 1; mask < 64; mask <<= 1) sv += __shfl_xor(sv, mask, 64);
  if ((t & 63) == 0) red[t >> 6] = sv;
  __syncthreads();
  if (t == 0) {
    float tot = red[0] + red[1] + red[2] + red[3];
    ((h2 >= 512) ? rsh : rsr)[h] = tot;
  }
}

// ---------------------------------------------------------------------------
// Gate GEMM + fused tanh/dot epilogue (unchanged — not the bottleneck yet)
// ---------------------------------------------------------------------------
__global__ __launch_bounds__(512, 4) void k_gate(
    const float* __restrict__ facts, const float* __restrict__ questions,
    const float* __restrict__ prevM, const float* __restrict__ z1b,
    const float* __restrict__ z2w, const unsigned short* __restrict__ Bp,
    float* __restrict__ logits) {
  __shared__ float qS[512], mS[512], z1bS[512], z2wS[512];
  __shared__ unsigned short At[64 * 40];
  __shared__ unsigned short Bt[16384];
  __shared__ float lp[64 * 4];
  const int tid = threadIdx.x;
  const int row0 = blockIdx.x * 64;
  const int b = row0 >> 8;
  const int s0 = row0 & 255;
  qS[tid] = questions[b * 512 + tid];
  mS[tid] = prevM[b * 512 + tid];
  z1bS[tid] = z1b[tid];
  z2wS[tid] = z2w[tid];
  const int w = tid >> 6, l = tid & 63;
  const int mgrp = w & 1, ngrp = w >> 1;
  const int lm = l & 15, lk = l >> 4;
  f32x4 acc[2][8];
#pragma unroll
  for (int a = 0; a < 2; ++a)
#pragma unroll
    for (int i = 0; i < 8; ++i) acc[a][i] = (f32x4){0.f, 0.f, 0.f, 0.f};
  const int arow = tid >> 3, ac = tid & 7;
  const float* fbase = facts + ((size_t)(b * 256 + s0 + arow)) * 512 + ac * 4;

  for (int kb = 0; kb < 64; ++kb) {
    __syncthreads();
    const int part = kb >> 4;          // 0: f*q, 1: f*m, 2: |f-q|, 3: |f-m|
    const int h0 = (kb & 15) * 32;
    f32x4 fv = *(const f32x4*)(fbase + h0);
    f32x4 ov = (part & 1) ? *(const f32x4*)&mS[h0 + ac * 4]
                          : *(const f32x4*)&qS[h0 + ac * 4];
    float z0, z1, z2, z3;
    if (part < 2) {
      z0 = fv[0] * ov[0]; z1 = fv[1] * ov[1];
      z2 = fv[2] * ov[2]; z3 = fv[3] * ov[3];
    } else {
      z0 = fabsf(fv[0] - ov[0]); z1 = fabsf(fv[1] - ov[1]);
      z2 = fabsf(fv[2] - ov[2]); z3 = fabsf(fv[3] - ov[3]);
    }
    unsigned p0 = (unsigned)f2bf(z0) | ((unsigned)f2bf(z1) << 16);
    unsigned p1 = (unsigned)f2bf(z2) | ((unsigned)f2bf(z3) << 16);
    u32x2 pk = {p0, p1};
    *(u32x2*)&At[arow * 40 + ac * 4] = pk;
    const char* bsrc = (const char*)Bp + (size_t)kb * 32768;
#pragma unroll
    for (int i = 0; i < 4; ++i)
      *(i32x4*)((char*)Bt + i * 8192 + tid * 16) =
          *(const i32x4*)(bsrc + i * 8192 + tid * 16);
    __syncthreads();
    bf16x8 af[2];
#pragma unroll
    for (int mi = 0; mi < 2; ++mi) {
      i32x4 av = *(const i32x4*)&At[((mgrp * 2 + mi) * 16 + lm) * 40 + lk * 8];
      af[mi] = __builtin_bit_cast(bf16x8, av);
    }
#pragma unroll
    for (int i = 0; i < 8; ++i) {
      const int nt = ngrp * 8 + i;
      i32x4 bv = *(const i32x4*)&Bt[lk * 4096 + (nt * 16 + lm) * 8];
      bf16x8 bf = __builtin_bit_cast(bf16x8, bv);
      acc[0][i] = __builtin_amdgcn_mfma_f32_16x16x32_bf16(af[0], bf, acc[0][i], 0, 0, 0);
      acc[1][i] = __builtin_amdgcn_mfma_f32_16x16x32_bf16(af[1], bf, acc[1][i], 0, 0, 0);
    }
  }
  float pr_[2][4];
#pragma unroll
  for (int mi = 0; mi < 2; ++mi)
#pragma unroll
    for (int r = 0; r < 4; ++r) pr_[mi][r] = 0.f;
#pragma unroll
  for (int i = 0; i < 8; ++i) {
    const int n_i = (ngrp * 8 + i) * 16 + lm;
    const float zb = z1bS[n_i], zw = z2wS[n_i];
#pragma unroll
    for (int mi = 0; mi < 2; ++mi)
#pragma unroll
      for (int r = 0; r < 4; ++r)
        pr_[mi][r] += fast_tanh(acc[mi][i][r] + zb) * zw;
  }
#pragma unroll
  for (int mask = 1; mask < 16; mask <<= 1)
#pragma unroll
    for (int mi = 0; mi < 2; ++mi)
#pragma unroll
      for (int r = 0; r < 4; ++r)
        pr_[mi][r] += __shfl_xor(pr_[mi][r], mask, 64);
  if (lm == 0) {
#pragma unroll
    for (int mi = 0; mi < 2; ++mi)
#pragma unroll
      for (int r = 0; r < 4; ++r)
        lp[((mgrp * 2 + mi) * 16 + lk * 4 + r) * 4 + ngrp] = pr_[mi][r];
  }
  __syncthreads();
  if (tid < 64)
    logits[row0 + tid] =
        lp[tid * 4] + lp[tid * 4 + 1] + lp[tid * 4 + 2] + lp[tid * 4 + 3];
}

// ---------------------------------------------------------------------------
// Softmax over S per batch (z2_b dropped: shift-invariant, exact)
// ---------------------------------------------------------------------------
__global__ void k_softmax(const float* __restrict__ logits,
                          float* __restrict__ G) {
  __shared__ float red[4], red2[4];
  int b = blockIdx.x, t = threadIdx.x;
  float v = logits[b * 256 + t];
  float mx = v;
#pragma unroll
  for (int mask = 1; mask < 64; mask <<= 1)
    mx = fmaxf(mx, __shfl_xor(mx, mask, 64));
  if ((t & 63) == 0) red[t >> 6] = mx;
  __syncthreads();
  mx = fmaxf(fmaxf(red[0], red[1]), fmaxf(red[2], red[3]));
  float e = __expf(v - mx);
  float sm = e;
#pragma unroll
  for (int mask = 1; mask < 64; mask <<= 1) sm += __shfl_xor(sm, mask, 64);
  if ((t & 63) == 0) red2[t >> 6] = sm;
  __syncthreads();
  sm = red2[0] + red2[1] + red2[2] + red2[3];
  G[b * 256 + t] = e / sm;
}

// ---------------------------------------------------------------------------
// Scan v8: FLAGLESS tag-validated exchange.
//
// 64 blocks = 8 groups x 8 members (g = blk&7: XCD-locality heuristic only).
// Member owns 64-wide n-slice, weights VGPR-resident. Exchange: publish C
// as f32 with the 2 LSBs of EVERY word stamped s&3; consumers gather with
// relaxed agent loads and retry until all 16 tags match. This removes the
// producer vmcnt drain, the flag store, the acquire/buffer_inv poll storm,
// and one barrier — the exchange is ONE validated round-trip.
//
// Safety (2 parity buffers + 2-bit tag): publishing s+2 (overwriting the
// parity-s buffer) requires validated-gather of all members' s+1, which
// requires every member published s+1, which requires they validated s —
// so every consumer extracted step-s data before any overwrite. Tags of
// s and s-2 differ mod 4; pre-scan garbage is poisoned 0xFF (tag 3, first
// expected tags 0,1; buffers fully rewritten before tag 3 recurs at s=3).
//
// Per step: [place gathered bf16 -> A] BAR1 | MFMA -> outb BAR2 |
// ew (waves 0-3): update Cv, stamp tags, 2x8B relaxed publish (fly) |
// prefetch | gather (wave w <-> member w): 8x8B relaxed loads, validate
// 16 tags, retry with s_sleep(2); convert f32->bf16 packed regs.
// ---------------------------------------------------------------------------
__global__ __launch_bounds__(512, 1) void k_scan(
    const float* __restrict__ facts, const float* __restrict__ Gm,
    const unsigned short* __restrict__ PB, const float* __restrict__ rsr,
    const float* __restrict__ rsh, const float* __restrict__ br,
    const float* __restrict__ bur, const float* __restrict__ bw,
    const float* __restrict__ bu, u64* __restrict__ EXq,
    float* __restrict__ Cb) {
  __shared__ __align__(16) unsigned short A[16 * 520];  // 16 x 512 bf16, 1040B pitch
  __shared__ float outb[8 * 272];                       // [w][row16 pitch17]
  const int tid = threadIdx.x;
  const int g = blockIdx.x & 7;    // group
  const int mem = blockIdx.x >> 3; // member / n-slice owner
  const int w = tid >> 6, l = tid & 63;
  const int lm = l & 15, lk = (l >> 4) & 3;
  // zero A (valid C_0 = 0 for step 0's MFMA)
  for (int i = tid; i < 2080; i += 512) ((u64*)A)[i] = 0ull;
  // weight fragments resident in VGPRs: this wave = (mat = w>>2, nt = w&3)
  i32x4 bfr[16];
  const char* pb = (const char*)PB + (size_t)(mem * 8 + w) * 16384;
#pragma unroll
  for (int kt = 0; kt < 16; ++kt)
    bfr[kt] = *(const i32x4*)(pb + kt * 1024 + l * 16);
  // elementwise lane (tid<256): thread owns (bb, 4 consecutive n)
  const int bb = tid >> 4;           // 0..15
  const int nq = tid & 15;
  const int n0 = mem * 64 + nq * 4;  // global n base
  f32x4 c_rsr, c_br, c_rsh, c_bw, c_bur, c_bu;
  const float* fptr = nullptr;
  const float* gptr = nullptr;
  f32x4 Cv = (f32x4){0.f, 0.f, 0.f, 0.f};
  f32x4 fct;
  float gval = 0.f;
  if (tid < 256) {
    c_rsr = *(const f32x4*)(rsr + n0);
    c_br  = *(const f32x4*)(br + n0);
    c_rsh = *(const f32x4*)(rsh + n0);
    c_bw  = *(const f32x4*)(bw + n0);
    c_bur = *(const f32x4*)(bur + n0);
    c_bu  = *(const f32x4*)(bu + n0);
    const int batch = g * 16 + bb;
    fptr = facts + (size_t)batch * 131072 + n0;
    gptr = Gm + batch * 256;
    fct = *(const f32x4*)(fptr);   // step-0 prefetch
    gval = gptr[0];
  }
  // gather mapping: wave w <-> member w; lane l owns (batch gb, 16-f32 run gq)
  const int gb = l >> 2;             // batch row 0..15
  const int gq = l & 3;              // 16-f32 quarter within the 64-n slice
  // carried packed bf16 (16 values = 8 u32) from last gather
  unsigned pk0 = 0, pk1 = 0, pk2 = 0, pk3 = 0, pk4 = 0, pk5 = 0, pk6 = 0,
           pk7 = 0;
  __syncthreads();  // prologue drain (A zeroed, weights loaded)

#pragma unroll 1
  for (int s = 0; s < 256; ++s) {
    // ---- [A] place gathered C (bf16, validated last step) into A ----
    if (s > 0) {
      char* dA = (char*)A + gb * 1040 + w * 128 + gq * 32;
      i32x4 v0 = {(int)pk0, (int)pk1, (int)pk2, (int)pk3};
      i32x4 v1 = {(int)pk4, (int)pk5, (int)pk6, (int)pk7};
      *(i32x4*)dA = v0;
      *(i32x4*)(dA + 16) = v1;
    }
    bar_lgkm();  // BAR1: A fully assembled
    // ---- [B] matvec: (C @ Ur | C @ U) slice via MFMA, two ILP chains ----
    f32x4 acc0 = (f32x4){0.f, 0.f, 0.f, 0.f};
    f32x4 acc1 = (f32x4){0.f, 0.f, 0.f, 0.f};
#pragma unroll
    for (int kt = 0; kt < 16; ++kt) {
      i32x4 av = *(const i32x4*)&A[lm * 520 + kt * 32 + lk * 8];
      bf16x8 afv = __builtin_bit_cast(bf16x8, av);
      bf16x8 bfv = __builtin_bit_cast(bf16x8, bfr[kt]);
      if (kt & 1)
        acc1 = __builtin_amdgcn_mfma_f32_16x16x32_bf16(afv, bfv, acc1, 0, 0, 0);
      else
        acc0 = __builtin_amdgcn_mfma_f32_16x16x32_bf16(afv, bfv, acc0, 0, 0, 0);
    }
    f32x4 accs = acc0 + acc1;
#pragma unroll
    for (int r = 0; r < 4; ++r)
      outb[w * 272 + (lk * 4 + r) * 17 + lm] = accs[r];
    bar_lgkm();  // BAR2: outb ready; all A reads done
    const unsigned tg = (unsigned)(s & 3);
    const unsigned pbase = ((unsigned)(s & 1) * 8u + (unsigned)g) * 8u;
    // ---- [C] elementwise update + tag-stamped f32 publish (flies) ----
    if (tid < 256) {
      unsigned uw[4];
#pragma unroll
      for (int r = 0; r < 4; ++r) {
        const int n_loc = nq * 4 + r;
        const float uro = outb[(n_loc >> 4) * 272 + bb * 17 + (n_loc & 15)];
        const float uuo = outb[(4 + (n_loc >> 4)) * 272 + bb * 17 + (n_loc & 15)];
        const float pr = fct[r] * c_rsr[r] + c_br[r];
        const float ph = fct[r] * c_rsh[r] + c_bw[r];
        const float r_ = fast_sigmoid(pr + uro + c_bur[r]);
        const float ht = fast_tanh(ph + r_ * (uuo + c_bu[r]));
        Cv[r] = gval * ht + (1.0f - gval) * Cv[r];
        uw[r] = (__builtin_bit_cast(unsigned, Cv[r]) & ~3u) | tg;
      }
      if (s < 255) {
        const u64 w0 = (u64)uw[0] | ((u64)uw[1] << 32);
        const u64 w1 = (u64)uw[2] | ((u64)uw[3] << 32);
        u64* dst = EXq + ((pbase + (unsigned)mem) * 512u +
                          (unsigned)(bb * 32 + nq * 2));
        __hip_atomic_store(dst, w0, __ATOMIC_RELAXED, __HIP_MEMORY_SCOPE_AGENT);
        __hip_atomic_store(dst + 1, w1, __ATOMIC_RELAXED,
                           __HIP_MEMORY_SCOPE_AGENT);
      }
    }
    // compiler fence: publishes issue before the gather spin
    asm volatile("" ::: "memory");
    __builtin_amdgcn_sched_barrier(0);
    if (s < 255) {
      // ---- [D] prefetch next-step inputs (fly; drained inside gather) ----
      if (tid < 256) {
        fct = *(const f32x4*)(fptr + (size_t)(s + 1) * 512);
        gval = gptr[s + 1];
      }
      // ---- [E] tag-validated gather: wave w reads member w's f32 slice ----
      const u64* src = EXq + ((pbase + (unsigned)w) * 512u +
                              (unsigned)(gb * 32 + gq * 8));
      u64 q0, q1, q2, q3, q4, q5, q6, q7;
      int guard = 0;
      bool ok;
      do {
        q0 = __hip_atomic_load(src + 0, __ATOMIC_RELAXED, __HIP_MEMORY_SCOPE_AGENT);
        q1 = __hip_atomic_load(src + 1, __ATOMIC_RELAXED, __HIP_MEMORY_SCOPE_AGENT);
        q2 = __hip_atomic_load(src + 2, __ATOMIC_RELAXED, __HIP_MEMORY_SCOPE_AGENT);
        q3 = __hip_atomic_load(src + 3, __ATOMIC_RELAXED, __HIP_MEMORY_SCOPE_AGENT);
        q4 = __hip_atomic_load(src + 4, __ATOMIC_RELAXED, __HIP_MEMORY_SCOPE_AGENT);
        q5 = __hip_atomic_load(src + 5, __ATOMIC_RELAXED, __HIP_MEMORY_SCOPE_AGENT);
        q6 = __hip_atomic_load(src + 6, __ATOMIC_RELAXED, __HIP_MEMORY_SCOPE_AGENT);
        q7 = __hip_atomic_load(src + 7, __ATOMIC_RELAXED, __HIP_MEMORY_SCOPE_AGENT);
        unsigned m = ((unsigned)q0 & 3u) ^ tg;
        m |= ((unsigned)(q0 >> 32) & 3u) ^ tg;
        m |= (((unsigned)q1 & 3u) ^ tg) | (((unsigned)(q1 >> 32) & 3u) ^ tg);
        m |= (((unsigned)q2 & 3u) ^ tg) | (((unsigned)(q2 >> 32) & 3u) ^ tg);
        m |= (((unsigned)q3 & 3u) ^ tg) | (((unsigned)(q3 >> 32) & 3u) ^ tg);
        m |= (((unsigned)q4 & 3u) ^ tg) | (((unsigned)(q4 >> 32) & 3u) ^ tg);
        m |= (((unsigned)q5 & 3u) ^ tg) | (((unsigned)(q5 >> 32) & 3u) ^ tg);
        m |= (((unsigned)q6 & 3u) ^ tg) | (((unsigned)(q6 >> 32) & 3u) ^ tg);
        m |= (((unsigned)q7 & 3u) ^ tg) | (((unsigned)(q7 >> 32) & 3u) ^ tg);
        ok = (m == 0u);
        if (!ok) __builtin_amdgcn_s_sleep(2);
      } while (!ok && ++guard < (1 << 16));  // bounded: bail -> wrong, no hang
      // convert 16 f32 -> 16 bf16 packed (placed at next step's [A])
#define PKW(Q)                                                              \
  ((unsigned)f2bf(__builtin_bit_cast(float, (unsigned)(Q))) |               \
   ((unsigned)f2bf(__builtin_bit_cast(float, (unsigned)((Q) >> 32))) << 16))
      pk0 = PKW(q0); pk1 = PKW(q1); pk2 = PKW(q2); pk3 = PKW(q3);
      pk4 = PKW(q4); pk5 = PKW(q5); pk6 = PKW(q6); pk7 = PKW(q7);
#undef PKW
    }
  }
  if (tid < 256) *(f32x4*)(Cb + (size_t)(g * 16 + bb) * 512 + n0) = Cv;
}

// ---------------------------------------------------------------------------
// Final: out[b] = relu([prevM | C | questions] @ nm_w + nm_b). 2 batches/WG.
// ---------------------------------------------------------------------------
__global__ __launch_bounds__(512) void k_final(
    const float* __restrict__ prevM, const float* __restrict__ questions,
    const float* __restrict__ Cb, const float* __restrict__ nmw,
    const float* __restrict__ nmb, float* __restrict__ out) {
  __shared__ float cc[2][1536];
  const int t = threadIdx.x;
  const int b0 = blockIdx.x * 2;
  for (int i = t; i < 1536; i += 512) {
#pragma unroll
    for (int bi = 0; bi < 2; ++bi) {
      int bbx = b0 + bi;
      float v;
      if (i < 512) v = prevM[bbx * 512 + i];
      else if (i < 1024) v = Cb[bbx * 512 + i - 512];
      else v = questions[bbx * 512 + i - 1024];
      cc[bi][i] = v;
    }
  }
  __syncthreads();
  const int h = t;
  float a0 = nmb[h], a1 = nmb[h];
#pragma unroll 4
  for (int f = 0; f < 1536; ++f) {
    float wv = nmw[f * 512 + h];
    a0 = fmaf(cc[0][f], wv, a0);
    a1 = fmaf(cc[1][f], wv, a1);
  }
  out[(size_t)b0 * 512 + h] = fmaxf(a0, 0.f);
  out[(size_t)(b0 + 1) * 512 + h] = fmaxf(a1, 0.f);
}

// ---------------------------------------------------------------------------
extern "C" void kernel_launch(void* const* d_in, const int* in_sizes, int n_in,
                              void* d_out, int out_size, void* d_ws,
                              size_t ws_size, hipStream_t stream) {
  const float* facts     = (const float*)d_in[0];
  const float* questions = (const float*)d_in[1];
  const float* prevM     = (const float*)d_in[2];
  const float* z1w       = (const float*)d_in[3];
  const float* z1b       = (const float*)d_in[4];
  const float* z2w       = (const float*)d_in[5];
  // d_in[6] = z2_b: softmax shift-invariant, unused (exact)
  const float* Wr        = (const float*)d_in[7];
  const float* br        = (const float*)d_in[8];
  const float* Ur        = (const float*)d_in[9];
  const float* bur       = (const float*)d_in[10];
  const float* W         = (const float*)d_in[11];
  const float* bw        = (const float*)d_in[12];
  const float* U         = (const float*)d_in[13];
  const float* bu        = (const float*)d_in[14];
  const float* nmw       = (const float*)d_in[15];
  const float* nmb       = (const float*)d_in[16];

  char* ws = (char*)d_ws;
  float* G             = (float*)(ws + OFF_G);
  float* rsr           = (float*)(ws + OFF_RSR);
  float* rsh           = (float*)(ws + OFF_RSH);
  u64* EXq             = (u64*)(ws + OFF_EX);
  float* Cb            = (float*)(ws + OFF_CBUF);
  float* logits        = (float*)(ws + OFF_LOGITS);
  unsigned short* Bp   = (unsigned short*)(ws + OFF_BP);
  unsigned short* PB   = (unsigned short*)(ws + OFF_PB);

  k_prep_bp<<<2048, 512, 0, stream>>>(z1w, Bp);
  k_prep_pb<<<1024, 512, 0, stream>>>(Ur, U, PB);
  k_prep_rs<<<1024, 256, 0, stream>>>(Wr, W, rsr, rsh);
  k_gate<<<512, 512, 0, stream>>>(facts, questions, prevM, z1b, z2w, Bp, logits);
  k_softmax<<<128, 256, 0, stream>>>(logits, G);
  // EX aliases Bp (dead after k_gate): poison 0xFF (tag=3) stream-ordered
  hipMemsetAsync(EXq, 0xFF, 524288, stream);
  k_scan<<<64, 512, 0, stream>>>(facts, G, PB, rsr, rsh, br, bur, bw, bu, EXq,
                                 Cb);
  k_final<<<64, 512, 0, stream>>>(prevM, questions, Cb, nmw, nmb, (float*)d_out);
}